// Round 10
// baseline (323.494 us; speedup 1.0000x reference)
//
#include <hip/hip_runtime.h>

typedef unsigned long long u64;

#define K_TOP 5000
#define NMS_THR_F 0.4f
#define CONF_THR_F 0.6f
#define W_WORDS 80          // ceil(5000/64)=79, padded to 80
#define ROWS_PAD 5056       // mat rows allocated
#define DIAG_N 5120         // band rows allocated (covers group 19 reach 5119)
#define BAND_W 4            // band words per row
#define CHUNK 8192          // elements per block in select pass
#define TPB 256

// ---------------- pass 1: per-block count of score>thr ----------------
__global__ __launch_bounds__(TPB)
void count_kernel(const float* __restrict__ conf, int N, int* __restrict__ counts) {
  int tid = threadIdx.x;
  long long base = (long long)blockIdx.x * CHUNK + (long long)tid * 32;
  int cnt = 0;
  if (base + 32 <= N) {
    const float4* c4 = (const float4*)conf;
    long long f0 = base >> 1;            // float4 index (2 anchors per float4)
    #pragma unroll
    for (int k = 0; k < 16; ++k) {
      float4 v = c4[f0 + k];
      cnt += (v.y > CONF_THR_F);
      cnt += (v.w > CONF_THR_F);
    }
  } else {
    for (int k = 0; k < 32; ++k) {
      long long n = base + k;
      if (n < N) cnt += (conf[2*n+1] > CONF_THR_F);
    }
  }
  __shared__ int s[TPB];
  s[tid] = cnt; __syncthreads();
  for (int d = TPB/2; d > 0; d >>= 1) {
    if (tid < d) s[tid] += s[tid+d];
    __syncthreads();
  }
  if (tid == 0) counts[blockIdx.x] = s[0];
}

// ---------------- pass 2: exclusive scan of block counts ----------------
__global__ __launch_bounds__(TPB)
void scan_kernel(const int* __restrict__ counts, int* __restrict__ offsets,
                 int* __restrict__ meta, int NB) {
  __shared__ int s[TPB];
  __shared__ int carry;
  int tid = threadIdx.x;
  if (tid == 0) carry = 0;
  __syncthreads();
  for (int base = 0; base < NB; base += TPB) {
    int idx = base + tid;
    int c = (idx < NB) ? counts[idx] : 0;
    s[tid] = c; __syncthreads();
    for (int d = 1; d < TPB; d <<= 1) {
      int v = (tid >= d) ? s[tid - d] : 0;
      __syncthreads();
      s[tid] += v;
      __syncthreads();
    }
    int excl = s[tid] - c + carry;
    if (idx < NB) offsets[idx] = excl;
    __syncthreads();                       // all threads done reading carry
    if (tid == 0) carry += s[TPB-1];
    __syncthreads();
  }
  if (tid == 0) {
    int total = carry;
    meta[0] = total < K_TOP ? total : K_TOP;  // M = number of valid slots
    meta[1] = total;
  }
}

// ---------------- pass 3: stable compaction of first K indices ----------------
__global__ __launch_bounds__(TPB)
void emit_kernel(const float* __restrict__ conf, int N,
                 const int* __restrict__ offsets, int* __restrict__ sel) {
  int tid = threadIdx.x;
  int boff = offsets[blockIdx.x];          // uniform
  if (boff >= K_TOP) return;               // uniform exit, before any barrier
  long long base = (long long)blockIdx.x * CHUNK + (long long)tid * 32;
  unsigned mbits = 0;
  if (base + 32 <= N) {
    const float4* c4 = (const float4*)conf;
    long long f0 = base >> 1;
    #pragma unroll
    for (int k = 0; k < 16; ++k) {
      float4 v = c4[f0 + k];
      mbits |= (unsigned)(v.y > CONF_THR_F) << (2*k);
      mbits |= (unsigned)(v.w > CONF_THR_F) << (2*k+1);
    }
  } else {
    for (int k = 0; k < 32; ++k) {
      long long n = base + k;
      if (n < N && conf[2*n+1] > CONF_THR_F) mbits |= 1u << k;
    }
  }
  int cnt = __popc(mbits);
  __shared__ int s[TPB];
  s[tid] = cnt; __syncthreads();
  for (int d = 1; d < TPB; d <<= 1) {
    int v = (tid >= d) ? s[tid - d] : 0;
    __syncthreads();
    s[tid] += v;
    __syncthreads();
  }
  int rank = boff + s[tid] - cnt;          // exclusive prefix within block + block offset
  if (mbits && rank < K_TOP) {
    for (int k = 0; k < 32; ++k) {
      if ((mbits >> k) & 1u) {
        if (rank < K_TOP) sel[rank] = (int)(base + k);
        ++rank;
      }
    }
  }
}

// scalar inputs arrive as 1-element arrays; dtype could be int32 or float32.
__device__ __forceinline__ float scalar_to_float(const int* p) {
  int iv = *p;
  float fv = __int_as_float(iv);
  return (iv > 0 && iv < (1 << 20)) ? (float)iv : fv;
}

// ---------------- pass 4: decode boxes/landms/conf for the <=5000 survivors ----
__global__ __launch_bounds__(TPB)
void decode_kernel(const float* __restrict__ loc, const float* __restrict__ conf,
                   const float* __restrict__ landms, const float* __restrict__ priors,
                   const int* __restrict__ psx, const int* __restrict__ psy,
                   const int* __restrict__ sel, const int* __restrict__ meta, int P,
                   float4* __restrict__ boxes, float2* __restrict__ cs,
                   float* __restrict__ pts) {
  int rank = blockIdx.x * TPB + threadIdx.x;
  if (rank >= K_TOP) return;
  int M = meta[0];
  if (rank >= M) {
    boxes[rank] = make_float4(0.f, 0.f, 0.f, 0.f);
    cs[rank] = make_float2(0.f, 0.f);
    #pragma unroll
    for (int k = 0; k < 10; ++k) pts[rank*10 + k] = 0.f;
    return;
  }
  int n = sel[rank];
  int pi = n % P;
  float sx = scalar_to_float(psx), sy = scalar_to_float(psy);
  float4 pr = ((const float4*)priors)[pi];
  float4 lo = ((const float4*)loc)[n];
  float cx = __fadd_rn(pr.x, __fmul_rn(__fmul_rn(lo.x, 0.1f), pr.z));
  float cy = __fadd_rn(pr.y, __fmul_rn(__fmul_rn(lo.y, 0.1f), pr.w));
  float w  = __fmul_rn(pr.z, expf(__fmul_rn(lo.z, 0.2f)));
  float h  = __fmul_rn(pr.w, expf(__fmul_rn(lo.w, 0.2f)));
  float hw = __fmul_rn(w, 0.5f), hh = __fmul_rn(h, 0.5f);
  float4 b;
  b.x = __fmul_rn(__fsub_rn(cx, hw), sx);
  b.y = __fmul_rn(__fsub_rn(cy, hh), sy);
  b.z = __fmul_rn(__fadd_rn(cx, hw), sx);
  b.w = __fmul_rn(__fadd_rn(cy, hh), sy);
  boxes[rank] = b;
  cs[rank] = ((const float2*)conf)[n];
  const float2* l2 = (const float2*)landms;
  #pragma unroll
  for (int k = 0; k < 5; ++k) {
    float2 lm = l2[(long long)n*5 + k];
    float px = __fmul_rn(__fadd_rn(pr.x, __fmul_rn(__fmul_rn(pr.z, lm.x), 0.1f)), sx);
    float py = __fmul_rn(__fadd_rn(pr.y, __fmul_rn(__fmul_rn(pr.w, lm.y), 0.1f)), sy);
    pts[rank*10 + 2*k]     = px;
    pts[rank*10 + 2*k + 1] = py;
  }
}

// ---------------- pass 5: suppression bit-matrix + 4-wide diag band -----------
__device__ __forceinline__ float box_area(float4 a) {
  return __fmul_rn(fmaxf(__fsub_rn(a.z, a.x), 0.f), fmaxf(__fsub_rn(a.w, a.y), 0.f));
}

__global__ __launch_bounds__(64)
void iou_kernel(const float4* __restrict__ boxes, u64* __restrict__ mat,
                u64* __restrict__ band) {
  int cb = blockIdx.x;            // col word 0..79
  int rb = blockIdx.y;            // row block 0..78
  int t  = threadIdx.x;
  __shared__ float4 cbox[64];
  __shared__ float  carea[64];
  int j0 = cb * 64;
  int jj = j0 + t;
  float4 bj = (jj < K_TOP) ? boxes[jj] : make_float4(0.f, 0.f, 0.f, 0.f);
  cbox[t]  = bj;
  carea[t] = box_area(bj);
  __syncthreads();
  int i = rb * 64 + t;
  if (i >= K_TOP) return;
  size_t widx = (size_t)i * W_WORDS + cb;
  int cbd = cb - rb;
  if (j0 + 63 <= i) {                    // whole word is j<=i (only cbd<=0 here)
    mat[widx] = 0ull;
    if (cbd == 0) band[(size_t)i * BAND_W] = 0ull;
    return;
  }
  float4 bi = boxes[i];
  float ai = box_area(bi);
  u64 bits = 0;
  #pragma unroll 8
  for (int q = 0; q < 64; ++q) {
    float4 b = cbox[q];
    float iw = fmaxf(__fsub_rn(fminf(bi.z, b.z), fmaxf(bi.x, b.x)), 0.f);
    float ih = fmaxf(__fsub_rn(fminf(bi.w, b.w), fmaxf(bi.y, b.y)), 0.f);
    float inter = __fmul_rn(iw, ih);
    float uni = __fsub_rn(__fadd_rn(ai, carea[q]), inter);
    float iou = __fdiv_rn(inter, fmaxf(uni, 1e-12f));
    int j = j0 + q;
    bits |= (u64)((iou > NMS_THR_F) & (j > i)) << q;
  }
  mat[widx] = bits;
  if (cbd >= 0 && cbd < BAND_W) band[(size_t)i * BAND_W + cbd] = bits;
}

// ---------------- pass 6: greedy reduce, 4-block-group band resolve -----------
// Single wave. Groups of 256 rows (4 blocks) resolve ENTIRELY in registers:
// band[i][0..3] (= mat[i][blk(i)..blk(i)+3]) is prefetched one group ahead
// into named regs (double-buffered). Kept rows' full 640-B masks are fetched
// 16 at a time (32 parallel plain loads -> one waitcnt). Serial latency
// events: ~2 per group x 20 groups, vs ~107 in the per-block version.
__device__ __forceinline__ u64 readlane_u64(u64 v, int lane) {
  unsigned lo = (unsigned)__builtin_amdgcn_readlane((int)(unsigned)(v & 0xffffffffull), lane);
  unsigned hi = (unsigned)__builtin_amdgcn_readlane((int)(unsigned)(v >> 32), lane);
  return ((u64)hi << 32) | lo;
}

#define NBLK 79
#define NG 20               // ceil(79/4)

#define DECL_BAND(P) u64 P##00=0,P##01=0,P##02=0,P##03=0,P##10=0,P##11=0,P##12=0,P##13=0, \
                         P##20=0,P##21=0,P##22=0,P##23=0,P##30=0,P##31=0,P##32=0,P##33=0;

#define LOAD_BAND(P, G) do { if ((G) < NG) {                                   \
  const u64* bp_ = band + ((size_t)(G) * 256 + lane) * BAND_W;                 \
  P##00 = bp_[0];   P##01 = bp_[1];   P##02 = bp_[2];   P##03 = bp_[3];        \
  P##10 = bp_[256]; P##11 = bp_[257]; P##12 = bp_[258]; P##13 = bp_[259];      \
  P##20 = bp_[512]; P##21 = bp_[513]; P##22 = bp_[514]; P##23 = bp_[515];      \
  P##30 = bp_[768]; P##31 = bp_[769]; P##32 = bp_[770]; P##33 = bp_[771];      \
} } while (0)

// forward-only scan, block 0..3; every pick is a global keep
#define RESOLVE(P) do {                                                        \
  while (a0) { int r_ = (int)__builtin_ctzll(a0); km0 |= 1ull << r_;           \
    u64 q0_=readlane_u64(P##00,r_), q1_=readlane_u64(P##01,r_),                \
        q2_=readlane_u64(P##02,r_), q3_=readlane_u64(P##03,r_);                \
    a0 &= ~(q0_ | (1ull << r_)); a1 &= ~q1_; a2 &= ~q2_; a3 &= ~q3_; }         \
  while (a1) { int r_ = (int)__builtin_ctzll(a1); km1 |= 1ull << r_;           \
    u64 q0_=readlane_u64(P##10,r_), q1_=readlane_u64(P##11,r_),                \
        q2_=readlane_u64(P##12,r_);                                            \
    a1 &= ~(q0_ | (1ull << r_)); a2 &= ~q1_; a3 &= ~q2_; }                     \
  while (a2) { int r_ = (int)__builtin_ctzll(a2); km2 |= 1ull << r_;           \
    u64 q0_=readlane_u64(P##20,r_), q1_=readlane_u64(P##21,r_);                \
    a2 &= ~(q0_ | (1ull << r_)); a3 &= ~q1_; }                                 \
  while (a3) { int r_ = (int)__builtin_ctzll(a3); km3 |= 1ull << r_;           \
    u64 q0_=readlane_u64(P##30,r_);                                            \
    a3 &= ~(q0_ | (1ull << r_)); }                                             \
} while (0)

#define POP(RV) do { RV = -1;                                                            \
  if      (km0) { int r_=(int)__builtin_ctzll(km0); km0 &= km0-1; RV = gbase + r_; }     \
  else if (km1) { int r_=(int)__builtin_ctzll(km1); km1 &= km1-1; RV = gbase + 64 + r_; }\
  else if (km2) { int r_=(int)__builtin_ctzll(km2); km2 &= km2-1; RV = gbase + 128 + r_; }\
  else if (km3) { int r_=(int)__builtin_ctzll(km3); km3 &= km3-1; RV = gbase + 192 + r_; }\
} while (0)

#define FETCH_SLOT(RV, V0, V1) do {                                            \
  if (RV >= 0) { size_t b_ = (size_t)RV * W_WORDS;                             \
    V0 = mat[b_ + lane]; V1 = mat[b_ + 64 + (lane & 15)];                      \
  } else { V0 = 0; V1 = 0; }                                                   \
} while (0)

#define GROUP_BODY(P) do {                                                     \
  int w0_ = 4 * g;                                                             \
  u64 c0_ = (w0_     < 64) ? readlane_u64(r0w, w0_)      : readlane_u64(r1w, w0_ - 64); \
  u64 c1_ = (w0_ + 1 < 64) ? readlane_u64(r0w, w0_ + 1)  : readlane_u64(r1w, w0_ - 63); \
  u64 c2_ = (w0_ + 2 < 64) ? readlane_u64(r0w, w0_ + 2)  : readlane_u64(r1w, w0_ - 62); \
  u64 c3_ = (w0_ + 3 < 64) ? readlane_u64(r0w, w0_ + 3)  : readlane_u64(r1w, w0_ - 61); \
  a0 = ~c0_;                                                                   \
  a1 = (w0_ + 1 < NBLK) ? ~c1_ : 0ull;                                         \
  a2 = (w0_ + 2 < NBLK) ? ~c2_ : 0ull;                                         \
  a3 = (w0_ + 3 < NBLK) ? ~c3_ : 0ull;                                         \
  km0 = km1 = km2 = km3 = 0ull;                                                \
  RESOLVE(P);                                                                  \
  int gbase = g * 256;                                                         \
  while (km0 | km1 | km2 | km3) {                                              \
    int r0_,r1_,r2_,r3_,r4_,r5_,r6_,r7_,r8_,r9_,rA_,rB_,rC_,rD_,rE_,rF_;       \
    POP(r0_); POP(r1_); POP(r2_); POP(r3_); POP(r4_); POP(r5_); POP(r6_); POP(r7_); \
    POP(r8_); POP(r9_); POP(rA_); POP(rB_); POP(rC_); POP(rD_); POP(rE_); POP(rF_); \
    u64 x0,y0,x1,y1,x2,y2,x3,y3,x4,y4,x5,y5,x6,y6,x7,y7;                       \
    u64 x8,y8,x9,y9,xA,yA,xB,yB,xC,yC,xD,yD,xE,yE,xF,yF;                       \
    FETCH_SLOT(r0_,x0,y0); FETCH_SLOT(r1_,x1,y1); FETCH_SLOT(r2_,x2,y2); FETCH_SLOT(r3_,x3,y3); \
    FETCH_SLOT(r4_,x4,y4); FETCH_SLOT(r5_,x5,y5); FETCH_SLOT(r6_,x6,y6); FETCH_SLOT(r7_,x7,y7); \
    FETCH_SLOT(r8_,x8,y8); FETCH_SLOT(r9_,x9,y9); FETCH_SLOT(rA_,xA,yA); FETCH_SLOT(rB_,xB,yB); \
    FETCH_SLOT(rC_,xC,yC); FETCH_SLOT(rD_,xD,yD); FETCH_SLOT(rE_,xE,yE); FETCH_SLOT(rF_,xF,yF); \
    r0w |= ((x0|x1)|(x2|x3)) | ((x4|x5)|(x6|x7)) | ((x8|x9)|(xA|xB)) | ((xC|xD)|(xE|xF)); \
    r1w |= ((y0|y1)|(y2|y3)) | ((y4|y5)|(y6|y7)) | ((y8|y9)|(yA|yB)) | ((yC|yD)|(yE|yF)); \
  }                                                                            \
} while (0)

__global__ __launch_bounds__(64)
void nms_reduce_kernel(const u64* __restrict__ mat, const u64* __restrict__ band,
                       const int* __restrict__ meta, u64* __restrict__ keepw) {
  int lane = threadIdx.x;
  int M = meta[0];
  auto initw = [&](int w) -> u64 {
    int start = w * 64;
    if (M <= start) return ~0ull;        // fully invalid -> removed
    if (M >= start + 64) return 0ull;    // fully valid
    return (~0ull) << (M - start);       // bits >= M removed
  };
  u64 r0w = initw(lane);                 // removed-state word `lane`
  u64 r1w = (lane < 16) ? initw(64 + lane) : ~0ull;  // lanes 0..15: words 64..79

  u64 a0, a1, a2, a3, km0, km1, km2, km3;
  DECL_BAND(bA); DECL_BAND(bB);
  LOAD_BAND(bA, 0);
  for (int g = 0; g < NG; ++g) {
    if (g & 1) { LOAD_BAND(bA, g + 1); GROUP_BODY(bB); }
    else       { LOAD_BAND(bB, g + 1); GROUP_BODY(bA); }
  }
  keepw[lane] = ~r0w;
  if (lane < 16) keepw[64 + lane] = ~r1w;
}

// ---------------- pass 7: final masked write ----------------
__global__ __launch_bounds__(TPB)
void finalize_kernel(const float4* __restrict__ boxes, const float2* __restrict__ cs,
                     const float* __restrict__ pts, const u64* __restrict__ keepw,
                     float* __restrict__ out) {
  int rank = blockIdx.x * TPB + threadIdx.x;
  if (rank >= K_TOP) return;
  float m = ((keepw[rank >> 6] >> (rank & 63)) & 1ull) ? 1.0f : 0.0f;
  const int PTS_OFF  = K_TOP * 2;    // 10000
  const int BOX_OFF  = K_TOP * 12;   // 60000
  const int KEEP_OFF = K_TOP * 16;   // 80000
  float2 c = cs[rank];
  out[rank*2 + 0] = c.x * m;
  out[rank*2 + 1] = c.y * m;
  #pragma unroll
  for (int k = 0; k < 10; ++k) out[PTS_OFF + rank*10 + k] = pts[rank*10 + k] * m;
  float4 b = boxes[rank];
  out[BOX_OFF + rank*4 + 0] = b.x * m;
  out[BOX_OFF + rank*4 + 1] = b.y * m;
  out[BOX_OFF + rank*4 + 2] = b.z * m;
  out[BOX_OFF + rank*4 + 3] = b.w * m;
  out[KEEP_OFF + rank] = m;
}

extern "C" void kernel_launch(void* const* d_in, const int* in_sizes, int n_in,
                              void* d_out, int out_size, void* d_ws, size_t ws_size,
                              hipStream_t stream) {
  const float* loc    = (const float*)d_in[0];
  const float* conf   = (const float*)d_in[1];
  const float* landms = (const float*)d_in[2];
  const float* priors = (const float*)d_in[3];
  const int*   psx    = (const int*)d_in[4];
  const int*   psy    = (const int*)d_in[5];
  int P = in_sizes[3] / 4;
  int N = in_sizes[1] / 2;
  int NB = (N + CHUNK - 1) / CHUNK;

  char* ws = (char*)d_ws;
  size_t off = 0;
  u64*    mat    = (u64*)(ws + off);    off += (size_t)ROWS_PAD * W_WORDS * 8; // 3.24 MB
  u64*    band   = (u64*)(ws + off);    off += (size_t)DIAG_N * BAND_W * 8;    // 160 KB
  u64*    keepw  = (u64*)(ws + off);    off += (size_t)W_WORDS * 8;
  float4* boxes  = (float4*)(ws + off); off += (size_t)K_TOP * 16;
  float2* cs     = (float2*)(ws + off); off += (size_t)K_TOP * 8;
  float*  pts    = (float*)(ws + off);  off += (size_t)K_TOP * 40;
  int*    sel    = (int*)(ws + off);    off += (size_t)K_TOP * 4;
  int*    counts = (int*)(ws + off);    off += (size_t)NB * 4;
  int*    offs   = (int*)(ws + off);    off += (size_t)NB * 4;
  int*    meta   = (int*)(ws + off);    off += 64;

  count_kernel<<<NB, TPB, 0, stream>>>(conf, N, counts);
  scan_kernel<<<1, TPB, 0, stream>>>(counts, offs, meta, NB);
  emit_kernel<<<NB, TPB, 0, stream>>>(conf, N, offs, sel);
  int dgrid = (K_TOP + TPB - 1) / TPB;
  decode_kernel<<<dgrid, TPB, 0, stream>>>(loc, conf, landms, priors, psx, psy,
                                           sel, meta, P, boxes, cs, pts);
  dim3 ig(W_WORDS, (K_TOP + 63) / 64);   // 80 x 79
  iou_kernel<<<ig, 64, 0, stream>>>(boxes, mat, band);
  nms_reduce_kernel<<<1, 64, 0, stream>>>(mat, band, meta, keepw);
  finalize_kernel<<<dgrid, TPB, 0, stream>>>(boxes, cs, pts, keepw, (float*)d_out);
}

// Round 11
// 317.984 us; speedup vs baseline: 1.0173x; 1.0173x over previous
//
#include <hip/hip_runtime.h>

typedef unsigned long long u64;

#define K_TOP 5000
#define NMS_THR_F 0.4f
#define CONF_THR_F 0.6f
#define W_WORDS 80          // ceil(5000/64)=79, padded to 80
#define ROWS_PAD 5056       // mat rows allocated; rows 5000..5055 written ZERO
#define DIAG_N 5120         // band rows allocated
#define BAND_W 4            // band words per row
#define CHUNK 8192          // elements per block in select pass
#define TPB 256

// ---------------- pass 1: per-block count of score>thr ----------------
__global__ __launch_bounds__(TPB)
void count_kernel(const float* __restrict__ conf, int N, int* __restrict__ counts) {
  int tid = threadIdx.x;
  long long base = (long long)blockIdx.x * CHUNK + (long long)tid * 32;
  int cnt = 0;
  if (base + 32 <= N) {
    const float4* c4 = (const float4*)conf;
    long long f0 = base >> 1;            // float4 index (2 anchors per float4)
    #pragma unroll
    for (int k = 0; k < 16; ++k) {
      float4 v = c4[f0 + k];
      cnt += (v.y > CONF_THR_F);
      cnt += (v.w > CONF_THR_F);
    }
  } else {
    for (int k = 0; k < 32; ++k) {
      long long n = base + k;
      if (n < N) cnt += (conf[2*n+1] > CONF_THR_F);
    }
  }
  __shared__ int s[TPB];
  s[tid] = cnt; __syncthreads();
  for (int d = TPB/2; d > 0; d >>= 1) {
    if (tid < d) s[tid] += s[tid+d];
    __syncthreads();
  }
  if (tid == 0) counts[blockIdx.x] = s[0];
}

// ---------------- pass 2: exclusive scan of block counts ----------------
__global__ __launch_bounds__(TPB)
void scan_kernel(const int* __restrict__ counts, int* __restrict__ offsets,
                 int* __restrict__ meta, int NB) {
  __shared__ int s[TPB];
  __shared__ int carry;
  int tid = threadIdx.x;
  if (tid == 0) carry = 0;
  __syncthreads();
  for (int base = 0; base < NB; base += TPB) {
    int idx = base + tid;
    int c = (idx < NB) ? counts[idx] : 0;
    s[tid] = c; __syncthreads();
    for (int d = 1; d < TPB; d <<= 1) {
      int v = (tid >= d) ? s[tid - d] : 0;
      __syncthreads();
      s[tid] += v;
      __syncthreads();
    }
    int excl = s[tid] - c + carry;
    if (idx < NB) offsets[idx] = excl;
    __syncthreads();                       // all threads done reading carry
    if (tid == 0) carry += s[TPB-1];
    __syncthreads();
  }
  if (tid == 0) {
    int total = carry;
    meta[0] = total < K_TOP ? total : K_TOP;  // M = number of valid slots
    meta[1] = total;
  }
}

// ---------------- pass 3: stable compaction of first K indices ----------------
__global__ __launch_bounds__(TPB)
void emit_kernel(const float* __restrict__ conf, int N,
                 const int* __restrict__ offsets, int* __restrict__ sel) {
  int tid = threadIdx.x;
  int boff = offsets[blockIdx.x];          // uniform
  if (boff >= K_TOP) return;               // uniform exit, before any barrier
  long long base = (long long)blockIdx.x * CHUNK + (long long)tid * 32;
  unsigned mbits = 0;
  if (base + 32 <= N) {
    const float4* c4 = (const float4*)conf;
    long long f0 = base >> 1;
    #pragma unroll
    for (int k = 0; k < 16; ++k) {
      float4 v = c4[f0 + k];
      mbits |= (unsigned)(v.y > CONF_THR_F) << (2*k);
      mbits |= (unsigned)(v.w > CONF_THR_F) << (2*k+1);
    }
  } else {
    for (int k = 0; k < 32; ++k) {
      long long n = base + k;
      if (n < N && conf[2*n+1] > CONF_THR_F) mbits |= 1u << k;
    }
  }
  int cnt = __popc(mbits);
  __shared__ int s[TPB];
  s[tid] = cnt; __syncthreads();
  for (int d = 1; d < TPB; d <<= 1) {
    int v = (tid >= d) ? s[tid - d] : 0;
    __syncthreads();
    s[tid] += v;
    __syncthreads();
  }
  int rank = boff + s[tid] - cnt;          // exclusive prefix within block + block offset
  if (mbits && rank < K_TOP) {
    for (int k = 0; k < 32; ++k) {
      if ((mbits >> k) & 1u) {
        if (rank < K_TOP) sel[rank] = (int)(base + k);
        ++rank;
      }
    }
  }
}

// scalar inputs arrive as 1-element arrays; dtype could be int32 or float32.
__device__ __forceinline__ float scalar_to_float(const int* p) {
  int iv = *p;
  float fv = __int_as_float(iv);
  return (iv > 0 && iv < (1 << 20)) ? (float)iv : fv;
}

// ---------------- pass 4: decode boxes/landms/conf for the <=5000 survivors ----
__global__ __launch_bounds__(TPB)
void decode_kernel(const float* __restrict__ loc, const float* __restrict__ conf,
                   const float* __restrict__ landms, const float* __restrict__ priors,
                   const int* __restrict__ psx, const int* __restrict__ psy,
                   const int* __restrict__ sel, const int* __restrict__ meta, int P,
                   float4* __restrict__ boxes, float2* __restrict__ cs,
                   float* __restrict__ pts) {
  int rank = blockIdx.x * TPB + threadIdx.x;
  if (rank >= K_TOP) return;
  int M = meta[0];
  if (rank >= M) {
    boxes[rank] = make_float4(0.f, 0.f, 0.f, 0.f);
    cs[rank] = make_float2(0.f, 0.f);
    #pragma unroll
    for (int k = 0; k < 10; ++k) pts[rank*10 + k] = 0.f;
    return;
  }
  int n = sel[rank];
  int pi = n % P;
  float sx = scalar_to_float(psx), sy = scalar_to_float(psy);
  float4 pr = ((const float4*)priors)[pi];
  float4 lo = ((const float4*)loc)[n];
  float cx = __fadd_rn(pr.x, __fmul_rn(__fmul_rn(lo.x, 0.1f), pr.z));
  float cy = __fadd_rn(pr.y, __fmul_rn(__fmul_rn(lo.y, 0.1f), pr.w));
  float w  = __fmul_rn(pr.z, expf(__fmul_rn(lo.z, 0.2f)));
  float h  = __fmul_rn(pr.w, expf(__fmul_rn(lo.w, 0.2f)));
  float hw = __fmul_rn(w, 0.5f), hh = __fmul_rn(h, 0.5f);
  float4 b;
  b.x = __fmul_rn(__fsub_rn(cx, hw), sx);
  b.y = __fmul_rn(__fsub_rn(cy, hh), sy);
  b.z = __fmul_rn(__fadd_rn(cx, hw), sx);
  b.w = __fmul_rn(__fadd_rn(cy, hh), sy);
  boxes[rank] = b;
  cs[rank] = ((const float2*)conf)[n];
  const float2* l2 = (const float2*)landms;
  #pragma unroll
  for (int k = 0; k < 5; ++k) {
    float2 lm = l2[(long long)n*5 + k];
    float px = __fmul_rn(__fadd_rn(pr.x, __fmul_rn(__fmul_rn(pr.z, lm.x), 0.1f)), sx);
    float py = __fmul_rn(__fadd_rn(pr.y, __fmul_rn(__fmul_rn(pr.w, lm.y), 0.1f)), sy);
    pts[rank*10 + 2*k]     = px;
    pts[rank*10 + 2*k + 1] = py;
  }
}

// ---------------- pass 5: suppression bit-matrix + 4-wide diag band -----------
__device__ __forceinline__ float box_area(float4 a) {
  return __fmul_rn(fmaxf(__fsub_rn(a.z, a.x), 0.f), fmaxf(__fsub_rn(a.w, a.y), 0.f));
}

__global__ __launch_bounds__(64)
void iou_kernel(const float4* __restrict__ boxes, u64* __restrict__ mat,
                u64* __restrict__ band) {
  int cb = blockIdx.x;            // col word 0..79
  int rb = blockIdx.y;            // row block 0..78
  int t  = threadIdx.x;
  __shared__ float4 cbox[64];
  __shared__ float  carea[64];
  int j0 = cb * 64;
  int jj = j0 + t;
  float4 bj = (jj < K_TOP) ? boxes[jj] : make_float4(0.f, 0.f, 0.f, 0.f);
  cbox[t]  = bj;
  carea[t] = box_area(bj);
  __syncthreads();
  int i = rb * 64 + t;
  size_t widx = (size_t)i * W_WORDS + cb;
  int cbd = cb - rb;
  if (i >= K_TOP) {                      // rows 5000..5055: guaranteed-ZERO rows
    mat[widx] = 0ull;                    // (dummy target for empty fetch slots)
    if (cbd >= 0 && cbd < BAND_W) band[(size_t)i * BAND_W + cbd] = 0ull;
    return;
  }
  if (j0 + 63 <= i) {                    // whole word is j<=i (only cbd<=0 here)
    mat[widx] = 0ull;
    if (cbd == 0) band[(size_t)i * BAND_W] = 0ull;
    return;
  }
  float4 bi = boxes[i];
  float ai = box_area(bi);
  u64 bits = 0;
  #pragma unroll 8
  for (int q = 0; q < 64; ++q) {
    float4 b = cbox[q];
    float iw = fmaxf(__fsub_rn(fminf(bi.z, b.z), fmaxf(bi.x, b.x)), 0.f);
    float ih = fmaxf(__fsub_rn(fminf(bi.w, b.w), fmaxf(bi.y, b.y)), 0.f);
    float inter = __fmul_rn(iw, ih);
    float uni = __fsub_rn(__fadd_rn(ai, carea[q]), inter);
    float iou = __fdiv_rn(inter, fmaxf(uni, 1e-12f));
    int j = j0 + q;
    bits |= (u64)((iou > NMS_THR_F) & (j > i)) << q;
  }
  mat[widx] = bits;
  if (cbd >= 0 && cbd < BAND_W) band[(size_t)i * BAND_W + cbd] = bits;
}

// ---------------- pass 6: greedy reduce, 4-block-group band resolve -----------
// Single wave, __launch_bounds__(64,1) so ~170 VGPRs are available: the 32
// u64 fetch slots AND the 32 u64 double-buffered band stay simultaneously
// live (r10's VGPR=72 proved regalloc serialized the batch without this).
// Empty fetch slots branchlessly load the guaranteed-zero row K_TOP. Two
// empty asm statements pin all 32 loaded values live at one point, forcing
// all 32 loads to issue before any wait -> one latency event per batch.
__device__ __forceinline__ u64 readlane_u64(u64 v, int lane) {
  unsigned lo = (unsigned)__builtin_amdgcn_readlane((int)(unsigned)(v & 0xffffffffull), lane);
  unsigned hi = (unsigned)__builtin_amdgcn_readlane((int)(unsigned)(v >> 32), lane);
  return ((u64)hi << 32) | lo;
}

#define NBLK 79
#define NG 20               // ceil(79/4)

#define DECL_BAND(P) u64 P##00=0,P##01=0,P##02=0,P##03=0,P##10=0,P##11=0,P##12=0,P##13=0, \
                         P##20=0,P##21=0,P##22=0,P##23=0,P##30=0,P##31=0,P##32=0,P##33=0;

#define LOAD_BAND(P, G) do { if ((G) < NG) {                                   \
  const u64* bp_ = band + ((size_t)(G) * 256 + lane) * BAND_W;                 \
  P##00 = bp_[0];   P##01 = bp_[1];   P##02 = bp_[2];   P##03 = bp_[3];        \
  P##10 = bp_[256]; P##11 = bp_[257]; P##12 = bp_[258]; P##13 = bp_[259];      \
  P##20 = bp_[512]; P##21 = bp_[513]; P##22 = bp_[514]; P##23 = bp_[515];      \
  P##30 = bp_[768]; P##31 = bp_[769]; P##32 = bp_[770]; P##33 = bp_[771];      \
} } while (0)

// forward-only scan, block 0..3; every pick is a global keep
#define RESOLVE(P) do {                                                        \
  while (a0) { int r_ = (int)__builtin_ctzll(a0); km0 |= 1ull << r_;           \
    u64 q0_=readlane_u64(P##00,r_), q1_=readlane_u64(P##01,r_),                \
        q2_=readlane_u64(P##02,r_), q3_=readlane_u64(P##03,r_);                \
    a0 &= ~(q0_ | (1ull << r_)); a1 &= ~q1_; a2 &= ~q2_; a3 &= ~q3_; }         \
  while (a1) { int r_ = (int)__builtin_ctzll(a1); km1 |= 1ull << r_;           \
    u64 q0_=readlane_u64(P##10,r_), q1_=readlane_u64(P##11,r_),                \
        q2_=readlane_u64(P##12,r_);                                            \
    a1 &= ~(q0_ | (1ull << r_)); a2 &= ~q1_; a3 &= ~q2_; }                     \
  while (a2) { int r_ = (int)__builtin_ctzll(a2); km2 |= 1ull << r_;           \
    u64 q0_=readlane_u64(P##20,r_), q1_=readlane_u64(P##21,r_);                \
    a2 &= ~(q0_ | (1ull << r_)); a3 &= ~q1_; }                                 \
  while (a3) { int r_ = (int)__builtin_ctzll(a3); km3 |= 1ull << r_;           \
    u64 q0_=readlane_u64(P##30,r_);                                            \
    a3 &= ~(q0_ | (1ull << r_)); }                                             \
} while (0)

#define POP(RV) do { RV = -1;                                                            \
  if      (km0) { int r_=(int)__builtin_ctzll(km0); km0 &= km0-1; RV = gbase + r_; }     \
  else if (km1) { int r_=(int)__builtin_ctzll(km1); km1 &= km1-1; RV = gbase + 64 + r_; }\
  else if (km2) { int r_=(int)__builtin_ctzll(km2); km2 &= km2-1; RV = gbase + 128 + r_; }\
  else if (km3) { int r_=(int)__builtin_ctzll(km3); km3 &= km3-1; RV = gbase + 192 + r_; }\
} while (0)

// branchless: empty slot (RV<0) reads the guaranteed-zero row K_TOP
#define FETCH_SLOT(RV, V0, V1) do {                                            \
  size_t b_ = (size_t)((RV) >= 0 ? (RV) : K_TOP) * W_WORDS;                    \
  V0 = mat[b_ + lane]; V1 = mat[b_ + 64 + (lane & 15)];                        \
} while (0)

#define GROUP_BODY(P) do {                                                     \
  int w0_ = 4 * g;                                                             \
  u64 c0_ = (w0_     < 64) ? readlane_u64(r0w, w0_)      : readlane_u64(r1w, w0_ - 64); \
  u64 c1_ = (w0_ + 1 < 64) ? readlane_u64(r0w, w0_ + 1)  : readlane_u64(r1w, w0_ - 63); \
  u64 c2_ = (w0_ + 2 < 64) ? readlane_u64(r0w, w0_ + 2)  : readlane_u64(r1w, w0_ - 62); \
  u64 c3_ = (w0_ + 3 < 64) ? readlane_u64(r0w, w0_ + 3)  : readlane_u64(r1w, w0_ - 61); \
  a0 = ~c0_;                                                                   \
  a1 = (w0_ + 1 < NBLK) ? ~c1_ : 0ull;                                         \
  a2 = (w0_ + 2 < NBLK) ? ~c2_ : 0ull;                                         \
  a3 = (w0_ + 3 < NBLK) ? ~c3_ : 0ull;                                         \
  km0 = km1 = km2 = km3 = 0ull;                                                \
  RESOLVE(P);                                                                  \
  int gbase = g * 256;                                                         \
  while (km0 | km1 | km2 | km3) {                                              \
    int r0_,r1_,r2_,r3_,r4_,r5_,r6_,r7_,r8_,r9_,rA_,rB_,rC_,rD_,rE_,rF_;       \
    POP(r0_); POP(r1_); POP(r2_); POP(r3_); POP(r4_); POP(r5_); POP(r6_); POP(r7_); \
    POP(r8_); POP(r9_); POP(rA_); POP(rB_); POP(rC_); POP(rD_); POP(rE_); POP(rF_); \
    u64 x0,y0,x1,y1,x2,y2,x3,y3,x4,y4,x5,y5,x6,y6,x7,y7;                       \
    u64 x8,y8,x9,y9,xA,yA,xB,yB,xC,yC,xD,yD,xE,yE,xF,yF;                       \
    FETCH_SLOT(r0_,x0,y0); FETCH_SLOT(r1_,x1,y1); FETCH_SLOT(r2_,x2,y2); FETCH_SLOT(r3_,x3,y3); \
    FETCH_SLOT(r4_,x4,y4); FETCH_SLOT(r5_,x5,y5); FETCH_SLOT(r6_,x6,y6); FETCH_SLOT(r7_,x7,y7); \
    FETCH_SLOT(r8_,x8,y8); FETCH_SLOT(r9_,x9,y9); FETCH_SLOT(rA_,xA,yA); FETCH_SLOT(rB_,xB,yB); \
    FETCH_SLOT(rC_,xC,yC); FETCH_SLOT(rD_,xD,yD); FETCH_SLOT(rE_,xE,yE); FETCH_SLOT(rF_,xF,yF); \
    asm volatile("" : "+v"(x0),"+v"(x1),"+v"(x2),"+v"(x3),"+v"(x4),"+v"(x5),   \
                      "+v"(x6),"+v"(x7),"+v"(x8),"+v"(x9),"+v"(xA),"+v"(xB),   \
                      "+v"(xC),"+v"(xD),"+v"(xE),"+v"(xF));                    \
    asm volatile("" : "+v"(y0),"+v"(y1),"+v"(y2),"+v"(y3),"+v"(y4),"+v"(y5),   \
                      "+v"(y6),"+v"(y7),"+v"(y8),"+v"(y9),"+v"(yA),"+v"(yB),   \
                      "+v"(yC),"+v"(yD),"+v"(yE),"+v"(yF));                    \
    r0w |= ((x0|x1)|(x2|x3)) | ((x4|x5)|(x6|x7)) | ((x8|x9)|(xA|xB)) | ((xC|xD)|(xE|xF)); \
    r1w |= ((y0|y1)|(y2|y3)) | ((y4|y5)|(y6|y7)) | ((y8|y9)|(yA|yB)) | ((yC|yD)|(yE|yF)); \
  }                                                                            \
} while (0)

__global__ __launch_bounds__(64, 1)
void nms_reduce_kernel(const u64* __restrict__ mat, const u64* __restrict__ band,
                       const int* __restrict__ meta, u64* __restrict__ keepw) {
  int lane = threadIdx.x;
  int M = meta[0];
  auto initw = [&](int w) -> u64 {
    int start = w * 64;
    if (M <= start) return ~0ull;        // fully invalid -> removed
    if (M >= start + 64) return 0ull;    // fully valid
    return (~0ull) << (M - start);       // bits >= M removed
  };
  u64 r0w = initw(lane);                 // removed-state word `lane`
  u64 r1w = (lane < 16) ? initw(64 + lane) : ~0ull;  // lanes 0..15: words 64..79

  u64 a0, a1, a2, a3, km0, km1, km2, km3;
  DECL_BAND(bA); DECL_BAND(bB);
  LOAD_BAND(bA, 0);
  for (int g = 0; g < NG; ++g) {
    if (g & 1) { LOAD_BAND(bA, g + 1); GROUP_BODY(bB); }
    else       { LOAD_BAND(bB, g + 1); GROUP_BODY(bA); }
  }
  keepw[lane] = ~r0w;
  if (lane < 16) keepw[64 + lane] = ~r1w;
}

// ---------------- pass 7: final masked write ----------------
__global__ __launch_bounds__(TPB)
void finalize_kernel(const float4* __restrict__ boxes, const float2* __restrict__ cs,
                     const float* __restrict__ pts, const u64* __restrict__ keepw,
                     float* __restrict__ out) {
  int rank = blockIdx.x * TPB + threadIdx.x;
  if (rank >= K_TOP) return;
  float m = ((keepw[rank >> 6] >> (rank & 63)) & 1ull) ? 1.0f : 0.0f;
  const int PTS_OFF  = K_TOP * 2;    // 10000
  const int BOX_OFF  = K_TOP * 12;   // 60000
  const int KEEP_OFF = K_TOP * 16;   // 80000
  float2 c = cs[rank];
  out[rank*2 + 0] = c.x * m;
  out[rank*2 + 1] = c.y * m;
  #pragma unroll
  for (int k = 0; k < 10; ++k) out[PTS_OFF + rank*10 + k] = pts[rank*10 + k] * m;
  float4 b = boxes[rank];
  out[BOX_OFF + rank*4 + 0] = b.x * m;
  out[BOX_OFF + rank*4 + 1] = b.y * m;
  out[BOX_OFF + rank*4 + 2] = b.z * m;
  out[BOX_OFF + rank*4 + 3] = b.w * m;
  out[KEEP_OFF + rank] = m;
}

extern "C" void kernel_launch(void* const* d_in, const int* in_sizes, int n_in,
                              void* d_out, int out_size, void* d_ws, size_t ws_size,
                              hipStream_t stream) {
  const float* loc    = (const float*)d_in[0];
  const float* conf   = (const float*)d_in[1];
  const float* landms = (const float*)d_in[2];
  const float* priors = (const float*)d_in[3];
  const int*   psx    = (const int*)d_in[4];
  const int*   psy    = (const int*)d_in[5];
  int P = in_sizes[3] / 4;
  int N = in_sizes[1] / 2;
  int NB = (N + CHUNK - 1) / CHUNK;

  char* ws = (char*)d_ws;
  size_t off = 0;
  u64*    mat    = (u64*)(ws + off);    off += (size_t)ROWS_PAD * W_WORDS * 8; // 3.24 MB
  u64*    band   = (u64*)(ws + off);    off += (size_t)DIAG_N * BAND_W * 8;    // 160 KB
  u64*    keepw  = (u64*)(ws + off);    off += (size_t)W_WORDS * 8;
  float4* boxes  = (float4*)(ws + off); off += (size_t)K_TOP * 16;
  float2* cs     = (float2*)(ws + off); off += (size_t)K_TOP * 8;
  float*  pts    = (float*)(ws + off);  off += (size_t)K_TOP * 40;
  int*    sel    = (int*)(ws + off);    off += (size_t)K_TOP * 4;
  int*    counts = (int*)(ws + off);    off += (size_t)NB * 4;
  int*    offs   = (int*)(ws + off);    off += (size_t)NB * 4;
  int*    meta   = (int*)(ws + off);    off += 64;

  count_kernel<<<NB, TPB, 0, stream>>>(conf, N, counts);
  scan_kernel<<<1, TPB, 0, stream>>>(counts, offs, meta, NB);
  emit_kernel<<<NB, TPB, 0, stream>>>(conf, N, offs, sel);
  int dgrid = (K_TOP + TPB - 1) / TPB;
  decode_kernel<<<dgrid, TPB, 0, stream>>>(loc, conf, landms, priors, psx, psy,
                                           sel, meta, P, boxes, cs, pts);
  dim3 ig(W_WORDS, (K_TOP + 63) / 64);   // 80 x 79
  iou_kernel<<<ig, 64, 0, stream>>>(boxes, mat, band);
  nms_reduce_kernel<<<1, 64, 0, stream>>>(mat, band, meta, keepw);
  finalize_kernel<<<dgrid, TPB, 0, stream>>>(boxes, cs, pts, keepw, (float*)d_out);
}